// Round 15
// baseline (131.364 us; speedup 1.0000x reference)
//
#include <hip/hip_runtime.h>
#include <math.h>

// Shapelet distance + softmin pooling — R14 MFMA kernel, INSTRUMENTED 48x.
// x: (8, 8, 2048) f32, w: (32, 8, 32) f32
// out: [pred (8*256), d_min (8*256)] f32
//
// ROUND 15 = MEASUREMENT. R14 = 10.03us; with F~4.9us fixed overhead the
// kernel is ~5.1us vs ~1.2us model. Repeat the FULL body (staging + A/B/C)
// 48x: body = (dur-10)/47 from dur alone; dispatch >53us -> top-5 row with
// counters. Opaque SGPR zero in global indices (anti-hoist), keep-alive asm
// per repeat (anti-DCE). Last repeat feeds output -> absmax unchanged.

#define T_VALID 2017
#define K10 14.426950408889634f   // 10/ln2: exp(10*z) == exp2(K10*z)
#define BIG 1e30f
#define REPEATS 48

typedef __attribute__((ext_vector_type(8))) short bf16x8;
typedef __attribute__((ext_vector_type(4))) float f32x4;

union FragU { unsigned u[4]; uint4 q; bf16x8 v; };

__device__ __forceinline__ float fexp2(float v) {
    float r; asm("v_exp_f32 %0, %1" : "=v"(r) : "v"(v)); return r;
}
__device__ __forceinline__ unsigned cvtpk(float lo, float hi) {
    unsigned r; asm("v_cvt_pk_bf16_f32 %0, %1, %2" : "=v"(r) : "v"(lo), "v"(hi)); return r;
}

__global__ __launch_bounds__(512)
__attribute__((amdgpu_waves_per_eu(2, 2)))
void shapelet_mfma(
    const float* __restrict__ x,
    const float* __restrict__ w,
    float* __restrict__ out)
{
    __shared__ unsigned xs8[8 * 257 * 4];   // 8-shift bf16 chunk store, 32.9 KB
    __shared__ float ssl[2048];             // ss(t), BIG for t >= T_VALID
    __shared__ float red[8][16];
    __shared__ float gml[16];

    const int bid = blockIdx.x;         // 128 = b(8) * m(8) * ntile(2)
    const int b = bid >> 4;
    const int m = (bid >> 1) & 7;
    const int ntile = bid & 1;
    const int tid = threadIdx.x;        // 0..511
    const int lane = tid & 63;
    const int wv = tid >> 6;            // wave 0..7
    const int r = lane & 15;            // B-col / A-row
    const int q = lane >> 4;            // k-group 0..3

    const float* xr = x + (((b << 3) + m) << 11);
    const int n = (ntile << 4) + r;
    const float* wrow = w + (((n << 3) + m) << 5);

    int zero;
    asm volatile("s_mov_b32 %0, 0" : "=s"(zero));

    #pragma unroll 1
    for (int rep = 0; rep < REPEATS; ++rep) {

        // ---- w: 2 dwordx4/lane (opaque index) + shfl-reduced w2
        const float4 f0 = ((const float4*)wrow)[(q << 1) + zero];
        const float4 f1 = ((const float4*)wrow)[(q << 1) + 1 + zero];

        // ---- stage x: window regs -> ss + 8-shift bf16 chunks
        {
            const float4* x4g = (const float4*)xr;
            float xs[36];
            #pragma unroll
            for (int jj = 0; jj < 9; ++jj) {
                int idx = tid + jj + zero;
                idx = idx > 511 ? 511 : idx;
                const float4 v = x4g[idx];
                xs[4 * jj + 0] = v.x; xs[4 * jj + 1] = v.y;
                xs[4 * jj + 2] = v.z; xs[4 * jj + 3] = v.w;
            }
            #pragma unroll
            for (int k = 0; k < 4; ++k) {
                const int p = (tid << 2) + k;
                FragU ch;
                ch.u[0] = cvtpk(xs[k + 0], xs[k + 1]);
                ch.u[1] = cvtpk(xs[k + 2], xs[k + 3]);
                ch.u[2] = cvtpk(xs[k + 4], xs[k + 5]);
                ch.u[3] = cvtpk(xs[k + 6], xs[k + 7]);
                *(uint4*)&xs8[((p & 7) * 257 + (p >> 3)) << 2] = ch.q;
            }
            float sv0 = 0.0f;
            #pragma unroll
            for (int l = 0; l < 32; ++l) sv0 = fmaf(xs[l], xs[l], sv0);
            float sv[4];
            sv[0] = sv0;
            #pragma unroll
            for (int i = 1; i < 4; ++i)
                sv[i] = fmaf(xs[31 + i], xs[31 + i], sv[i - 1]) - xs[i - 1] * xs[i - 1];
            const int t0 = tid << 2;
            #pragma unroll
            for (int i = 0; i < 4; ++i)
                if (t0 + i >= T_VALID) sv[i] = BIG;
            f32x4 s4 = {sv[0], sv[1], sv[2], sv[3]};
            *(f32x4*)&ssl[t0] = s4;
        }

        // ---- B-frag + shfl-reduced w2
        FragU bf;
        bf.u[0] = cvtpk(f0.x, f0.y); bf.u[1] = cvtpk(f0.z, f0.w);
        bf.u[2] = cvtpk(f1.x, f1.y); bf.u[3] = cvtpk(f1.z, f1.w);
        float w2v = f0.x * f0.x;
        w2v = fmaf(f0.y, f0.y, w2v); w2v = fmaf(f0.z, f0.z, w2v);
        w2v = fmaf(f0.w, f0.w, w2v); w2v = fmaf(f1.x, f1.x, w2v);
        w2v = fmaf(f1.y, f1.y, w2v); w2v = fmaf(f1.z, f1.z, w2v);
        w2v = fmaf(f1.w, f1.w, w2v);
        w2v += __shfl_xor(w2v, 16);
        w2v += __shfl_xor(w2v, 32);

        __syncthreads();

        // ---- Phase A
        float dA[64];
        #pragma unroll
        for (int i = 0; i < 16; ++i) {
            const int tt = (wv << 4) + i;
            int b0 = (tt << 4) + r + (q << 3);
            b0 = b0 > 2040 ? 2040 : b0;
            FragU af;
            af.q = *(const uint4*)&xs8[((b0 & 7) * 257 + (b0 >> 3)) << 2];
            f32x4 z = {0.0f, 0.0f, 0.0f, 0.0f};
            const f32x4 acc = __builtin_amdgcn_mfma_f32_16x16x32_bf16(af.v, bf.v, z, 0, 0, 0);
            const f32x4 sv = *(const f32x4*)&ssl[(tt << 4) + (q << 2)];
            dA[4 * i + 0] = fmaf(-2.0f, acc[0], sv[0] + w2v);
            dA[4 * i + 1] = fmaf(-2.0f, acc[1], sv[1] + w2v);
            dA[4 * i + 2] = fmaf(-2.0f, acc[2], sv[2] + w2v);
            dA[4 * i + 3] = fmaf(-2.0f, acc[3], sv[3] + w2v);
        }

        // ---- Phase B: block-global min per n
        float m0 = dA[0];
        #pragma unroll
        for (int k = 1; k < 64; ++k) m0 = fminf(m0, dA[k]);
        m0 = fminf(m0, __shfl_xor(m0, 16));
        m0 = fminf(m0, __shfl_xor(m0, 32));
        if (lane < 16) red[wv][r] = m0;
        __syncthreads();
        if (tid < 16) {
            float g = red[0][tid];
            #pragma unroll
            for (int wq = 1; wq < 8; ++wq) g = fminf(g, red[wq][tid]);
            gml[tid] = g;
        }
        __syncthreads();

        // ---- Phase C
        const float g0 = gml[r];
        float sa0 = 0.0f, sa1 = 0.0f, sa2 = 0.0f, sa3 = 0.0f;
        #pragma unroll
        for (int k = 0; k < 64; k += 4) {
            sa0 += fexp2(K10 * (g0 - dA[k + 0]));
            sa1 += fexp2(K10 * (g0 - dA[k + 1]));
            sa2 += fexp2(K10 * (g0 - dA[k + 2]));
            sa3 += fexp2(K10 * (g0 - dA[k + 3]));
        }
        float S = (sa0 + sa1) + (sa2 + sa3);
        S += __shfl_xor(S, 16);
        S += __shfl_xor(S, 32);
        if (lane < 16) red[wv][r] = S;

        asm volatile("" :: "v"(S), "v"(m0));   // keep each repeat live
        __syncthreads();
    }

    // ---- final: sum 8 wave partials (from last repeat), write pred + dmin
    if (tid < 16) {
        float Ssum = red[0][tid];
        #pragma unroll
        for (int wq = 1; wq < 8; ++wq) Ssum += red[wq][tid];
        const float g = gml[tid];
        const int o = (b << 8) + (((ntile << 4) + tid) << 3) + m;
        out[o]        = expf(-g + 0.1f * logf(Ssum));
        out[2048 + o] = sqrtf(fmaxf(g, 0.0f));
    }
}

extern "C" void kernel_launch(void* const* d_in, const int* in_sizes, int n_in,
                              void* d_out, int out_size, void* d_ws, size_t ws_size,
                              hipStream_t stream) {
    const float* x = (const float*)d_in[0];   // (8,8,2048)
    const float* w = (const float*)d_in[1];   // (32,8,32)
    float* out = (float*)d_out;               // 4096 floats
    hipLaunchKernelGGL(shapelet_mfma, dim3(128), dim3(512), 0, stream, x, w, out);
}

// Round 16
// 16.449 us; speedup vs baseline: 7.9862x; 7.9862x over previous
//
#include <hip/hip_runtime.h>
#include <math.h>

// Shapelet distance + softmin pooling — MFMA, 1024-thread blocks.
// x: (8, 8, 2048) f32, w: (32, 8, 32) f32
// out: [pred (8*256), d_min (8*256)] f32
//
// d2(b,t,n,m) = ss(t) + w2(n,m) - 2*dot(t,n)  [ss,w2 exact f32; dot bf16 MFMA]
// Round 16: R15 measured body=2.58us, VALUBusy 31%, MfmaUtil 3.7%, occ 11%
// -> latency-bound at 2 waves/SIMD. Same structure as R14 but 16 waves/block
// (4/SIMD): wave owns 8 t-tiles (dA[32], lower VGPR pressure), staging on
// threads 0-511 (latency-bound, extra waves wouldn't help), 16-wave tree.

#define T_VALID 2017
#define K10 14.426950408889634f   // 10/ln2: exp(10*z) == exp2(K10*z)
#define BIG 1e30f

typedef __attribute__((ext_vector_type(8))) short bf16x8;
typedef __attribute__((ext_vector_type(4))) float f32x4;

union FragU { unsigned u[4]; uint4 q; bf16x8 v; };

__device__ __forceinline__ float fexp2(float v) {
    float r; asm("v_exp_f32 %0, %1" : "=v"(r) : "v"(v)); return r;
}
__device__ __forceinline__ unsigned cvtpk(float lo, float hi) {
    unsigned r; asm("v_cvt_pk_bf16_f32 %0, %1, %2" : "=v"(r) : "v"(lo), "v"(hi)); return r;
}

__global__ __launch_bounds__(1024)
__attribute__((amdgpu_waves_per_eu(4, 4)))
void shapelet_mfma(
    const float* __restrict__ x,
    const float* __restrict__ w,
    float* __restrict__ out)
{
    // 8-shift chunk store: xs8[s*257+i] (16B) = bf16 x[8i+s .. 8i+s+7].
    __shared__ unsigned xs8[8 * 257 * 4];   // 32.9 KB
    __shared__ float ssl[2048];             // ss(t), BIG for t >= T_VALID
    __shared__ float red[16][16];
    __shared__ float gml[16];

    const int bid = blockIdx.x;         // 128 = b(8) * m(8) * ntile(2)
    const int b = bid >> 4;
    const int m = (bid >> 1) & 7;
    const int ntile = bid & 1;
    const int tid = threadIdx.x;        // 0..1023
    const int lane = tid & 63;
    const int wv = tid >> 6;            // wave 0..15
    const int r = lane & 15;            // B-col (n in tile) / A-row
    const int q = lane >> 4;            // k-group 0..3

    const float* xr = x + (((b << 3) + m) << 11);   // 2048 f32

    // ---- w: lane loads only its frag slice (2 dwordx4)
    const int n = (ntile << 4) + r;
    const float* wrow = w + (((n << 3) + m) << 5);
    const float4 f0 = ((const float4*)wrow)[(q << 1)];
    const float4 f1 = ((const float4*)wrow)[(q << 1) + 1];

    // ---- stage x (threads 0..511): window regs -> ss + 8-shift bf16 chunks
    if (tid < 512) {
        const float4* x4g = (const float4*)xr;
        float xs[36];
        #pragma unroll
        for (int jj = 0; jj < 9; ++jj) {
            int idx = tid + jj;
            idx = idx > 511 ? 511 : idx;      // clamp: feeds only masked t
            const float4 v = x4g[idx];
            xs[4 * jj + 0] = v.x; xs[4 * jj + 1] = v.y;
            xs[4 * jj + 2] = v.z; xs[4 * jj + 3] = v.w;
        }
        // chunks p = 4*tid+k: bf16 x[p..p+7] -> row p&7, col p>>3
        #pragma unroll
        for (int k = 0; k < 4; ++k) {
            const int p = (tid << 2) + k;
            FragU ch;
            ch.u[0] = cvtpk(xs[k + 0], xs[k + 1]);
            ch.u[1] = cvtpk(xs[k + 2], xs[k + 3]);
            ch.u[2] = cvtpk(xs[k + 4], xs[k + 5]);
            ch.u[3] = cvtpk(xs[k + 6], xs[k + 7]);
            *(uint4*)&xs8[((p & 7) * 257 + (p >> 3)) << 2] = ch.q;
        }
        // sliding ss for t = 4*tid .. 4*tid+3 (4 chains + tree), masked -> BIG
        float c0 = 0.0f, c1 = 0.0f, c2 = 0.0f, c3 = 0.0f;
        #pragma unroll
        for (int l = 0; l < 32; l += 4) {
            c0 = fmaf(xs[l + 0], xs[l + 0], c0);
            c1 = fmaf(xs[l + 1], xs[l + 1], c1);
            c2 = fmaf(xs[l + 2], xs[l + 2], c2);
            c3 = fmaf(xs[l + 3], xs[l + 3], c3);
        }
        float sv[4];
        sv[0] = (c0 + c1) + (c2 + c3);
        #pragma unroll
        for (int i = 1; i < 4; ++i)
            sv[i] = fmaf(xs[31 + i], xs[31 + i], sv[i - 1]) - xs[i - 1] * xs[i - 1];
        const int t0 = tid << 2;
        #pragma unroll
        for (int i = 0; i < 4; ++i)
            if (t0 + i >= T_VALID) sv[i] = BIG;
        f32x4 s4 = {sv[0], sv[1], sv[2], sv[3]};
        *(f32x4*)&ssl[t0] = s4;
    }

    // ---- B-frag + shfl-reduced w2 (lanes with same r share n)
    FragU bf;
    bf.u[0] = cvtpk(f0.x, f0.y); bf.u[1] = cvtpk(f0.z, f0.w);
    bf.u[2] = cvtpk(f1.x, f1.y); bf.u[3] = cvtpk(f1.z, f1.w);
    float w2v = f0.x * f0.x;
    w2v = fmaf(f0.y, f0.y, w2v); w2v = fmaf(f0.z, f0.z, w2v);
    w2v = fmaf(f0.w, f0.w, w2v); w2v = fmaf(f1.x, f1.x, w2v);
    w2v = fmaf(f1.y, f1.y, w2v); w2v = fmaf(f1.z, f1.z, w2v);
    w2v = fmaf(f1.w, f1.w, w2v);
    w2v += __shfl_xor(w2v, 16);
    w2v += __shfl_xor(w2v, 32);

    __syncthreads();

    // ---- Phase A: 8 independent {b128 A-frag -> MFMA -> d2 regs} per wave
    float dA[32];
    #pragma unroll
    for (int i = 0; i < 8; ++i) {
        const int tt = (wv << 3) + i;               // t-tile 0..127
        int b0 = (tt << 4) + r + (q << 3);          // window start
        b0 = b0 > 2040 ? 2040 : b0;                 // clamp (masked rows only)
        FragU af;
        af.q = *(const uint4*)&xs8[((b0 & 7) * 257 + (b0 >> 3)) << 2];
        f32x4 z = {0.0f, 0.0f, 0.0f, 0.0f};
        const f32x4 acc = __builtin_amdgcn_mfma_f32_16x16x32_bf16(af.v, bf.v, z, 0, 0, 0);
        // C: col = lane&15 (=n), row = 4q + j -> t = 16tt + 4q + j
        const f32x4 sv = *(const f32x4*)&ssl[(tt << 4) + (q << 2)];
        dA[4 * i + 0] = fmaf(-2.0f, acc[0], sv[0] + w2v);
        dA[4 * i + 1] = fmaf(-2.0f, acc[1], sv[1] + w2v);
        dA[4 * i + 2] = fmaf(-2.0f, acc[2], sv[2] + w2v);
        dA[4 * i + 3] = fmaf(-2.0f, acc[3], sv[3] + w2v);
    }

    // ---- Phase B: block-global min per n
    float m0 = dA[0];
    #pragma unroll
    for (int k = 1; k < 32; ++k) m0 = fminf(m0, dA[k]);
    m0 = fminf(m0, __shfl_xor(m0, 16));
    m0 = fminf(m0, __shfl_xor(m0, 32));
    if (lane < 16) red[wv][r] = m0;
    __syncthreads();
    if (tid < 16) {
        float g = red[0][tid];
        #pragma unroll
        for (int wq = 1; wq < 16; ++wq) g = fminf(g, red[wq][tid]);
        gml[tid] = g;
    }
    __syncthreads();

    // ---- Phase C: 32 independent exps vs global min, 4-way accumulators
    const float g0 = gml[r];
    float sa0 = 0.0f, sa1 = 0.0f, sa2 = 0.0f, sa3 = 0.0f;
    #pragma unroll
    for (int k = 0; k < 32; k += 4) {
        sa0 += fexp2(K10 * (g0 - dA[k + 0]));
        sa1 += fexp2(K10 * (g0 - dA[k + 1]));
        sa2 += fexp2(K10 * (g0 - dA[k + 2]));
        sa3 += fexp2(K10 * (g0 - dA[k + 3]));
    }
    float S = (sa0 + sa1) + (sa2 + sa3);
    S += __shfl_xor(S, 16);
    S += __shfl_xor(S, 32);
    if (lane < 16) red[wv][r] = S;
    __syncthreads();

    // ---- final: sum 16 wave partials, write pred + dmin
    if (tid < 16) {
        float Ssum = red[0][tid];
        #pragma unroll
        for (int wq = 1; wq < 16; ++wq) Ssum += red[wq][tid];
        const float g = gml[tid];
        const int o = (b << 8) + (((ntile << 4) + tid) << 3) + m;
        out[o]        = expf(-g + 0.1f * logf(Ssum));
        out[2048 + o] = sqrtf(fmaxf(g, 0.0f));
    }
}

extern "C" void kernel_launch(void* const* d_in, const int* in_sizes, int n_in,
                              void* d_out, int out_size, void* d_ws, size_t ws_size,
                              hipStream_t stream) {
    const float* x = (const float*)d_in[0];   // (8,8,2048)
    const float* w = (const float*)d_in[1];   // (32,8,32)
    float* out = (float*)d_out;               // 4096 floats
    hipLaunchKernelGGL(shapelet_mfma, dim3(128), dim3(1024), 0, stream, x, w, out);
}

// Round 17
// 10.989 us; speedup vs baseline: 11.9543x; 1.4969x over previous
//
#include <hip/hip_runtime.h>
#include <math.h>

// Shapelet distance + softmin pooling — MFMA, wave-autonomous staging.
// x: (8, 8, 2048) f32, w: (32, 8, 32) f32
// out: [pred (8*256), d_min (8*256)] f32
//
// d2(b,t,n,m) = ss(t) + w2(n,m) - 2*dot(t,n)  [ss,w2 exact f32; dot bf16 MFMA]
// Round 17: R14 revert + decouple waves. R14's staging barrier exists ONLY
// for a 24-chunk overhang (wave wv's phase A reads chunks up to 256wv+279;
// own lanes stage [256wv,256wv+256)). Fix: lanes 0-5 of each wave stage the
// overhang redundantly (duplicate LDS writes = identical values, benign),
// then replace __syncthreads with wave-local lgkmcnt(0)+sched_barrier ->
// waves flow stage->MFMA independently; 2 waves/SIMD overlap each other's
// latency. (R16's 1024-thr lockstep experiment regressed; reverted.)

#define T_VALID 2017
#define K10 14.426950408889634f   // 10/ln2: exp(10*z) == exp2(K10*z)
#define BIG 1e30f

typedef __attribute__((ext_vector_type(8))) short bf16x8;
typedef __attribute__((ext_vector_type(4))) float f32x4;

union FragU { unsigned u[4]; uint4 q; bf16x8 v; };

__device__ __forceinline__ float fexp2(float v) {
    float r; asm("v_exp_f32 %0, %1" : "=v"(r) : "v"(v)); return r;
}
__device__ __forceinline__ unsigned cvtpk(float lo, float hi) {
    unsigned r; asm("v_cvt_pk_bf16_f32 %0, %1, %2" : "=v"(r) : "v"(lo), "v"(hi)); return r;
}

__global__ __launch_bounds__(512)
__attribute__((amdgpu_waves_per_eu(2, 2)))
void shapelet_mfma(
    const float* __restrict__ x,
    const float* __restrict__ w,
    float* __restrict__ out)
{
    // 8-shift chunk store: xs8[s*257+i] (16B) = bf16 x[8i+s .. 8i+s+7].
    __shared__ unsigned xs8[8 * 257 * 4];   // 32.9 KB
    __shared__ float ssl[2048];             // ss(t), BIG for t >= T_VALID
    __shared__ float red[8][16];
    __shared__ float gml[16];

    const int bid = blockIdx.x;         // 128 = b(8) * m(8) * ntile(2)
    const int b = bid >> 4;
    const int m = (bid >> 1) & 7;
    const int ntile = bid & 1;
    const int tid = threadIdx.x;        // 0..511
    const int lane = tid & 63;
    const int wv = tid >> 6;            // wave 0..7
    const int r = lane & 15;            // B-col (n in tile) / A-row
    const int q = lane >> 4;            // k-group 0..3

    const float* xr = x + (((b << 3) + m) << 11);   // 2048 f32
    const float4* x4g = (const float4*)xr;

    // ---- w: lane loads only its frag slice (2 dwordx4)
    const int n = (ntile << 4) + r;
    const float* wrow = w + (((n << 3) + m) << 5);
    const float4 f0 = ((const float4*)wrow)[(q << 1)];
    const float4 f1 = ((const float4*)wrow)[(q << 1) + 1];

    // ---- stage own region: window regs -> ss + 8-shift bf16 chunks
    {
        float xs[36];
        #pragma unroll
        for (int jj = 0; jj < 9; ++jj) {
            int idx = tid + jj;
            idx = idx > 511 ? 511 : idx;      // clamp: feeds only masked t
            const float4 v = x4g[idx];
            xs[4 * jj + 0] = v.x; xs[4 * jj + 1] = v.y;
            xs[4 * jj + 2] = v.z; xs[4 * jj + 3] = v.w;
        }
        // chunks p = 4*tid+k: bf16 x[p..p+7] -> row p&7, col p>>3
        #pragma unroll
        for (int k = 0; k < 4; ++k) {
            const int p = (tid << 2) + k;
            FragU ch;
            ch.u[0] = cvtpk(xs[k + 0], xs[k + 1]);
            ch.u[1] = cvtpk(xs[k + 2], xs[k + 3]);
            ch.u[2] = cvtpk(xs[k + 4], xs[k + 5]);
            ch.u[3] = cvtpk(xs[k + 6], xs[k + 7]);
            *(uint4*)&xs8[((p & 7) * 257 + (p >> 3)) << 2] = ch.q;
        }
        // sliding ss for t = 4*tid .. 4*tid+3 (4 chains + tree), masked -> BIG
        float c0 = 0.0f, c1 = 0.0f, c2 = 0.0f, c3 = 0.0f;
        #pragma unroll
        for (int l = 0; l < 32; l += 4) {
            c0 = fmaf(xs[l + 0], xs[l + 0], c0);
            c1 = fmaf(xs[l + 1], xs[l + 1], c1);
            c2 = fmaf(xs[l + 2], xs[l + 2], c2);
            c3 = fmaf(xs[l + 3], xs[l + 3], c3);
        }
        float sv[4];
        sv[0] = (c0 + c1) + (c2 + c3);
        #pragma unroll
        for (int i = 1; i < 4; ++i)
            sv[i] = fmaf(xs[31 + i], xs[31 + i], sv[i - 1]) - xs[i - 1] * xs[i - 1];
        const int t0 = tid << 2;
        #pragma unroll
        for (int i = 0; i < 4; ++i)
            if (t0 + i >= T_VALID) sv[i] = BIG;
        f32x4 s4 = {sv[0], sv[1], sv[2], sv[3]};
        *(f32x4*)&ssl[t0] = s4;
    }

    // ---- stage own wave's OVERHANG chunks p in [256wv+256, 256wv+280)
    // (phase A reads up to b0 = 256wv+279; duplicates of wave wv+1's own
    // writes with identical values -> benign race, removes the block barrier)
    if (wv < 7 && lane < 6) {
        const int p0 = (wv << 8) + 256 + (lane << 2);
        const float4 v0 = x4g[(p0 >> 2) + 0];
        const float4 v1 = x4g[(p0 >> 2) + 1];
        const float4 v2 = x4g[(p0 >> 2) + 2];
        float ys[12] = {v0.x, v0.y, v0.z, v0.w,
                        v1.x, v1.y, v1.z, v1.w,
                        v2.x, v2.y, v2.z, v2.w};
        #pragma unroll
        for (int k = 0; k < 4; ++k) {
            const int p = p0 + k;
            FragU ch;
            ch.u[0] = cvtpk(ys[k + 0], ys[k + 1]);
            ch.u[1] = cvtpk(ys[k + 2], ys[k + 3]);
            ch.u[2] = cvtpk(ys[k + 4], ys[k + 5]);
            ch.u[3] = cvtpk(ys[k + 6], ys[k + 7]);
            *(uint4*)&xs8[((p & 7) * 257 + (p >> 3)) << 2] = ch.q;
        }
    }

    // ---- B-frag + shfl-reduced w2 (lanes with same r share n)
    FragU bf;
    bf.u[0] = cvtpk(f0.x, f0.y); bf.u[1] = cvtpk(f0.z, f0.w);
    bf.u[2] = cvtpk(f1.x, f1.y); bf.u[3] = cvtpk(f1.z, f1.w);
    float w2v = f0.x * f0.x;
    w2v = fmaf(f0.y, f0.y, w2v); w2v = fmaf(f0.z, f0.z, w2v);
    w2v = fmaf(f0.w, f0.w, w2v); w2v = fmaf(f1.x, f1.x, w2v);
    w2v = fmaf(f1.y, f1.y, w2v); w2v = fmaf(f1.z, f1.z, w2v);
    w2v = fmaf(f1.w, f1.w, w2v);
    w2v += __shfl_xor(w2v, 16);
    w2v += __shfl_xor(w2v, 32);

    // wave-local ordering only: own LDS writes complete before own reads.
    asm volatile("s_waitcnt lgkmcnt(0)" ::: "memory");
    __builtin_amdgcn_sched_barrier(0);

    // ---- Phase A: 16 independent {b128 A-frag -> MFMA -> d2 regs}
    // wave wv reads ONLY chunks [256wv, 256wv+280) + ssl [256wv, 256wv+256)
    // -> all self-staged, no cross-wave dependency.
    float dA[64];
    #pragma unroll
    for (int i = 0; i < 16; ++i) {
        const int tt = (wv << 4) + i;               // t-tile 0..127
        int b0 = (tt << 4) + r + (q << 3);          // window start
        b0 = b0 > 2040 ? 2040 : b0;                 // clamp (masked rows only)
        FragU af;
        af.q = *(const uint4*)&xs8[((b0 & 7) * 257 + (b0 >> 3)) << 2];
        f32x4 z = {0.0f, 0.0f, 0.0f, 0.0f};
        const f32x4 acc = __builtin_amdgcn_mfma_f32_16x16x32_bf16(af.v, bf.v, z, 0, 0, 0);
        // C: col = lane&15 (=n), row = 4q + j -> t = 16tt + 4q + j
        const f32x4 sv = *(const f32x4*)&ssl[(tt << 4) + (q << 2)];
        dA[4 * i + 0] = fmaf(-2.0f, acc[0], sv[0] + w2v);
        dA[4 * i + 1] = fmaf(-2.0f, acc[1], sv[1] + w2v);
        dA[4 * i + 2] = fmaf(-2.0f, acc[2], sv[2] + w2v);
        dA[4 * i + 3] = fmaf(-2.0f, acc[3], sv[3] + w2v);
    }

    // ---- Phase B: block-global min per n
    float m0 = dA[0];
    #pragma unroll
    for (int k = 1; k < 64; ++k) m0 = fminf(m0, dA[k]);
    m0 = fminf(m0, __shfl_xor(m0, 16));
    m0 = fminf(m0, __shfl_xor(m0, 32));
    if (lane < 16) red[wv][r] = m0;
    __syncthreads();
    if (tid < 16) {
        float g = red[0][tid];
        #pragma unroll
        for (int wq = 1; wq < 8; ++wq) g = fminf(g, red[wq][tid]);
        gml[tid] = g;
    }
    __syncthreads();

    // ---- Phase C: 64 independent exps vs global min, 4-way accumulators
    const float g0 = gml[r];
    float sa0 = 0.0f, sa1 = 0.0f, sa2 = 0.0f, sa3 = 0.0f;
    #pragma unroll
    for (int k = 0; k < 64; k += 4) {
        sa0 += fexp2(K10 * (g0 - dA[k + 0]));
        sa1 += fexp2(K10 * (g0 - dA[k + 1]));
        sa2 += fexp2(K10 * (g0 - dA[k + 2]));
        sa3 += fexp2(K10 * (g0 - dA[k + 3]));
    }
    float S = (sa0 + sa1) + (sa2 + sa3);
    S += __shfl_xor(S, 16);
    S += __shfl_xor(S, 32);
    if (lane < 16) red[wv][r] = S;
    __syncthreads();

    // ---- final: sum 8 wave partials, write pred + dmin
    if (tid < 16) {
        float Ssum = red[0][tid];
        #pragma unroll
        for (int wq = 1; wq < 8; ++wq) Ssum += red[wq][tid];
        const float g = gml[tid];
        const int o = (b << 8) + (((ntile << 4) + tid) << 3) + m;
        out[o]        = expf(-g + 0.1f * logf(Ssum));
        out[2048 + o] = sqrtf(fmaxf(g, 0.0f));
    }
}

extern "C" void kernel_launch(void* const* d_in, const int* in_sizes, int n_in,
                              void* d_out, int out_size, void* d_ws, size_t ws_size,
                              hipStream_t stream) {
    const float* x = (const float*)d_in[0];   // (8,8,2048)
    const float* w = (const float*)d_in[1];   // (32,8,32)
    float* out = (float*)d_out;               // 4096 floats
    hipLaunchKernelGGL(shapelet_mfma, dim3(128), dim3(512), 0, stream, x, w, out);
}

// Round 18
// 10.586 us; speedup vs baseline: 12.4087x; 1.0380x over previous
//
#include <hip/hip_runtime.h>
#include <math.h>

// Shapelet distance + softmin pooling — MFMA, R14 base + wave-local softmin.
// x: (8, 8, 2048) f32, w: (32, 8, 32) f32
// out: [pred (8*256), d_min (8*256)] f32
//
// d2(b,t,n,m) = ss(t) + w2(n,m) - 2*dot(t,n)  [ss,w2 exact f32; dot bf16 MFMA]
// Round 18: R14 revert (10.03 best) + ONE structural change: phase B/C no
// longer waits for the BLOCK-global min (2 barriers + LDS round-trip before
// any exp could issue). Each wave uses its own wave-min as the exp scale
// (valid lower-bound reference; terms <= 1), runs its 64 quarter-rate v_exp
// immediately, then ONE final 8-way LSE merge. Removes a barrier + the
// inter-wave serialization on the slowest stager. (R16/R17 showed coupling
// changes in either direction elsewhere regress; this one is algorithmic.)

#define T_VALID 2017
#define K10 14.426950408889634f   // 10/ln2: exp(10*z) == exp2(K10*z)
#define BIG 1e30f

typedef __attribute__((ext_vector_type(8))) short bf16x8;
typedef __attribute__((ext_vector_type(4))) float f32x4;

union FragU { unsigned u[4]; uint4 q; bf16x8 v; };

__device__ __forceinline__ float fexp2(float v) {
    float r; asm("v_exp_f32 %0, %1" : "=v"(r) : "v"(v)); return r;
}
__device__ __forceinline__ unsigned cvtpk(float lo, float hi) {
    unsigned r; asm("v_cvt_pk_bf16_f32 %0, %1, %2" : "=v"(r) : "v"(lo), "v"(hi)); return r;
}
__device__ __forceinline__ void lse_merge(float& fm, float& fS, float om, float oS) {
    float nm = fminf(fm, om);
    fS = fmaf(fS, fexp2(K10 * (nm - fm)), oS * fexp2(K10 * (nm - om)));
    fm = nm;
}

__global__ __launch_bounds__(512)
__attribute__((amdgpu_waves_per_eu(2, 2)))
void shapelet_mfma(
    const float* __restrict__ x,
    const float* __restrict__ w,
    float* __restrict__ out)
{
    // 8-shift chunk store: xs8[s*257+i] (16B) = bf16 x[8i+s .. 8i+s+7].
    __shared__ unsigned xs8[8 * 257 * 4];   // 32.9 KB
    __shared__ float ssl[2048];             // ss(t), BIG for t >= T_VALID
    __shared__ float redm[8][16], redS[8][16];

    const int bid = blockIdx.x;         // 128 = b(8) * m(8) * ntile(2)
    const int b = bid >> 4;
    const int m = (bid >> 1) & 7;
    const int ntile = bid & 1;
    const int tid = threadIdx.x;        // 0..511
    const int lane = tid & 63;
    const int wv = tid >> 6;            // wave 0..7
    const int r = lane & 15;            // B-col (n in tile) / A-row
    const int q = lane >> 4;            // k-group 0..3

    const float* xr = x + (((b << 3) + m) << 11);   // 2048 f32

    // ---- w: lane loads only its frag slice (2 dwordx4)
    const int n = (ntile << 4) + r;
    const float* wrow = w + (((n << 3) + m) << 5);
    const float4 f0 = ((const float4*)wrow)[(q << 1)];
    const float4 f1 = ((const float4*)wrow)[(q << 1) + 1];

    // ---- stage x: window regs -> ss + 8-shift bf16 chunks
    {
        const float4* x4g = (const float4*)xr;
        float xs[36];
        #pragma unroll
        for (int jj = 0; jj < 9; ++jj) {
            int idx = tid + jj;
            idx = idx > 511 ? 511 : idx;      // clamp: feeds only masked t
            const float4 v = x4g[idx];
            xs[4 * jj + 0] = v.x; xs[4 * jj + 1] = v.y;
            xs[4 * jj + 2] = v.z; xs[4 * jj + 3] = v.w;
        }
        // chunks p = 4*tid+k: bf16 x[p..p+7] -> row p&7, col p>>3
        #pragma unroll
        for (int k = 0; k < 4; ++k) {
            const int p = (tid << 2) + k;
            FragU ch;
            ch.u[0] = cvtpk(xs[k + 0], xs[k + 1]);
            ch.u[1] = cvtpk(xs[k + 2], xs[k + 3]);
            ch.u[2] = cvtpk(xs[k + 4], xs[k + 5]);
            ch.u[3] = cvtpk(xs[k + 6], xs[k + 7]);
            *(uint4*)&xs8[((p & 7) * 257 + (p >> 3)) << 2] = ch.q;
        }
        // sliding ss for t = 4*tid .. 4*tid+3 (4 chains + tree), masked -> BIG
        float c0 = 0.0f, c1 = 0.0f, c2 = 0.0f, c3 = 0.0f;
        #pragma unroll
        for (int l = 0; l < 32; l += 4) {
            c0 = fmaf(xs[l + 0], xs[l + 0], c0);
            c1 = fmaf(xs[l + 1], xs[l + 1], c1);
            c2 = fmaf(xs[l + 2], xs[l + 2], c2);
            c3 = fmaf(xs[l + 3], xs[l + 3], c3);
        }
        float sv[4];
        sv[0] = (c0 + c1) + (c2 + c3);
        #pragma unroll
        for (int i = 1; i < 4; ++i)
            sv[i] = fmaf(xs[31 + i], xs[31 + i], sv[i - 1]) - xs[i - 1] * xs[i - 1];
        const int t0 = tid << 2;
        #pragma unroll
        for (int i = 0; i < 4; ++i)
            if (t0 + i >= T_VALID) sv[i] = BIG;
        f32x4 s4 = {sv[0], sv[1], sv[2], sv[3]};
        *(f32x4*)&ssl[t0] = s4;
    }

    // ---- B-frag + shfl-reduced w2 (lanes with same r share n)
    FragU bf;
    bf.u[0] = cvtpk(f0.x, f0.y); bf.u[1] = cvtpk(f0.z, f0.w);
    bf.u[2] = cvtpk(f1.x, f1.y); bf.u[3] = cvtpk(f1.z, f1.w);
    float w2v = f0.x * f0.x;
    w2v = fmaf(f0.y, f0.y, w2v); w2v = fmaf(f0.z, f0.z, w2v);
    w2v = fmaf(f0.w, f0.w, w2v); w2v = fmaf(f1.x, f1.x, w2v);
    w2v = fmaf(f1.y, f1.y, w2v); w2v = fmaf(f1.z, f1.z, w2v);
    w2v = fmaf(f1.w, f1.w, w2v);
    w2v += __shfl_xor(w2v, 16);
    w2v += __shfl_xor(w2v, 32);

    __syncthreads();

    // ---- Phase A: 16 independent {b128 A-frag -> MFMA -> d2 regs}
    float dA[64];
    #pragma unroll
    for (int i = 0; i < 16; ++i) {
        const int tt = (wv << 4) + i;               // t-tile 0..127
        int b0 = (tt << 4) + r + (q << 3);          // window start
        b0 = b0 > 2040 ? 2040 : b0;                 // clamp (masked rows only)
        FragU af;
        af.q = *(const uint4*)&xs8[((b0 & 7) * 257 + (b0 >> 3)) << 2];
        f32x4 z = {0.0f, 0.0f, 0.0f, 0.0f};
        const f32x4 acc = __builtin_amdgcn_mfma_f32_16x16x32_bf16(af.v, bf.v, z, 0, 0, 0);
        // C: col = lane&15 (=n), row = 4q + j -> t = 16tt + 4q + j
        const f32x4 sv = *(const f32x4*)&ssl[(tt << 4) + (q << 2)];
        dA[4 * i + 0] = fmaf(-2.0f, acc[0], sv[0] + w2v);
        dA[4 * i + 1] = fmaf(-2.0f, acc[1], sv[1] + w2v);
        dA[4 * i + 2] = fmaf(-2.0f, acc[2], sv[2] + w2v);
        dA[4 * i + 3] = fmaf(-2.0f, acc[3], sv[3] + w2v);
    }

    // ---- Phase B (wave-local): min over own 64 d2 + 16-lane-group reduce
    float m0 = dA[0];
    #pragma unroll
    for (int k = 1; k < 64; ++k) m0 = fminf(m0, dA[k]);
    m0 = fminf(m0, __shfl_xor(m0, 16));
    m0 = fminf(m0, __shfl_xor(m0, 32));   // wave-min for this n (lower bound)

    // ---- Phase C (wave-local): 64 exps vs wave-min, 4-way accumulators
    float sa0 = 0.0f, sa1 = 0.0f, sa2 = 0.0f, sa3 = 0.0f;
    #pragma unroll
    for (int k = 0; k < 64; k += 4) {
        sa0 += fexp2(K10 * (m0 - dA[k + 0]));
        sa1 += fexp2(K10 * (m0 - dA[k + 1]));
        sa2 += fexp2(K10 * (m0 - dA[k + 2]));
        sa3 += fexp2(K10 * (m0 - dA[k + 3]));
    }
    float S = (sa0 + sa1) + (sa2 + sa3);
    S += __shfl_xor(S, 16);
    S += __shfl_xor(S, 32);
    if (lane < 16) { redm[wv][r] = m0; redS[wv][r] = S; }
    __syncthreads();

    // ---- final: single 8-way LSE merge per n, write pred + dmin
    if (tid < 16) {
        float fm = redm[0][tid], fS = redS[0][tid];
        #pragma unroll
        for (int wq = 1; wq < 8; ++wq)
            lse_merge(fm, fS, redm[wq][tid], redS[wq][tid]);
        const int o = (b << 8) + (((ntile << 4) + tid) << 3) + m;
        out[o]        = expf(-fm + 0.1f * logf(fS));
        out[2048 + o] = sqrtf(fmaxf(fm, 0.0f));
    }
}

extern "C" void kernel_launch(void* const* d_in, const int* in_sizes, int n_in,
                              void* d_out, int out_size, void* d_ws, size_t ws_size,
                              hipStream_t stream) {
    const float* x = (const float*)d_in[0];   // (8,8,2048)
    const float* w = (const float*)d_in[1];   // (32,8,32)
    float* out = (float*)d_out;               // 4096 floats
    hipLaunchKernelGGL(shapelet_mfma, dim3(128), dim3(512), 0, stream, x, w, out);
}

// Round 19
// 10.009 us; speedup vs baseline: 13.1240x; 1.0576x over previous
//
#include <hip/hip_runtime.h>
#include <math.h>

// Shapelet distance + softmin pooling — MFMA, single kernel (R14, final).
// x: (8, 8, 2048) f32, w: (32, 8, 32) f32
// out: [pred (8*256), d_min (8*256)] f32
//
// d2(b,t,n,m) = ss(t) + w2(n,m) - 2*dot(t,n)  [ss,w2 exact f32; dot bf16 MFMA]
// pred = exp(-d2min + log(S)/10); dmin = sqrt(d2min)
//
// FINAL (= round 14, measured best 10.03us). Decomposition from R6/R15
// instrumentation: dur ~= 4.9us harness graph-replay overhead (unreachable)
// + ~2.5us launch ramp / cold path + 2.6us latency-bound body (VALUBusy 31%,
// MfmaUtil 3.7%, 2 waves/SIMD). All 5 attempted body restructures (R16-R18:
// 16 waves, barrier removal, wave-local softmin) regressed; remaining
// headroom (~1.5us) is below the prediction resolution of the model.

#define T_VALID 2017
#define K10 14.426950408889634f   // 10/ln2: exp(10*z) == exp2(K10*z)
#define BIG 1e30f

typedef __attribute__((ext_vector_type(8))) short bf16x8;
typedef __attribute__((ext_vector_type(4))) float f32x4;

union FragU { unsigned u[4]; uint4 q; bf16x8 v; };

__device__ __forceinline__ float fexp2(float v) {
    float r; asm("v_exp_f32 %0, %1" : "=v"(r) : "v"(v)); return r;
}
__device__ __forceinline__ unsigned cvtpk(float lo, float hi) {
    unsigned r; asm("v_cvt_pk_bf16_f32 %0, %1, %2" : "=v"(r) : "v"(lo), "v"(hi)); return r;
}

__global__ __launch_bounds__(512)
__attribute__((amdgpu_waves_per_eu(2, 2)))
void shapelet_mfma(
    const float* __restrict__ x,
    const float* __restrict__ w,
    float* __restrict__ out)
{
    // 8-shift chunk store: xs8[s*257+i] (16B) = bf16 x[8i+s .. 8i+s+7].
    // Window start b0 -> one aligned ds_read_b128 at (s=b0&7, i=b0>>3).
    __shared__ unsigned xs8[8 * 257 * 4];   // 32.9 KB
    __shared__ float ssl[2048];             // ss(t), BIG for t >= T_VALID
    __shared__ float red[8][16];
    __shared__ float gml[16];

    const int bid = blockIdx.x;         // 128 = b(8) * m(8) * ntile(2)
    const int b = bid >> 4;
    const int m = (bid >> 1) & 7;
    const int ntile = bid & 1;
    const int tid = threadIdx.x;        // 0..511
    const int lane = tid & 63;
    const int wv = tid >> 6;            // wave 0..7
    const int r = lane & 15;            // B-col (n within tile) / A-row
    const int q = lane >> 4;            // k-group 0..3

    const float* xr = x + (((b << 3) + m) << 11);   // 2048 f32

    // ---- w: lane loads ONLY its frag slice (2 dwordx4); w2 via shfl reduce
    const int n = (ntile << 4) + r;
    const float* wrow = w + (((n << 3) + m) << 5);
    const float4 f0 = ((const float4*)wrow)[(q << 1)];
    const float4 f1 = ((const float4*)wrow)[(q << 1) + 1];

    // ---- stage x: window regs -> ss + 8-shift bf16 chunks
    {
        const float4* x4g = (const float4*)xr;
        float xs[36];
        #pragma unroll
        for (int jj = 0; jj < 9; ++jj) {
            int idx = tid + jj;
            idx = idx > 511 ? 511 : idx;      // clamp: feeds only masked t
            const float4 v = x4g[idx];
            xs[4 * jj + 0] = v.x; xs[4 * jj + 1] = v.y;
            xs[4 * jj + 2] = v.z; xs[4 * jj + 3] = v.w;
        }
        // chunks p = 4*tid+k: bf16 x[p..p+7] -> row p&7, col p>>3
        #pragma unroll
        for (int k = 0; k < 4; ++k) {
            const int p = (tid << 2) + k;
            FragU ch;
            ch.u[0] = cvtpk(xs[k + 0], xs[k + 1]);
            ch.u[1] = cvtpk(xs[k + 2], xs[k + 3]);
            ch.u[2] = cvtpk(xs[k + 4], xs[k + 5]);
            ch.u[3] = cvtpk(xs[k + 6], xs[k + 7]);
            *(uint4*)&xs8[((p & 7) * 257 + (p >> 3)) << 2] = ch.q;
        }
        // sliding ss for t = 4*tid .. 4*tid+3, masked tail -> BIG
        float sv0 = 0.0f;
        #pragma unroll
        for (int l = 0; l < 32; ++l) sv0 = fmaf(xs[l], xs[l], sv0);
        float sv[4];
        sv[0] = sv0;
        #pragma unroll
        for (int i = 1; i < 4; ++i)
            sv[i] = fmaf(xs[31 + i], xs[31 + i], sv[i - 1]) - xs[i - 1] * xs[i - 1];
        const int t0 = tid << 2;
        #pragma unroll
        for (int i = 0; i < 4; ++i)
            if (t0 + i >= T_VALID) sv[i] = BIG;
        f32x4 s4 = {sv[0], sv[1], sv[2], sv[3]};
        *(f32x4*)&ssl[t0] = s4;
    }

    // ---- B-frag + shfl-reduced w2 (lanes with same r share n)
    FragU bf;
    bf.u[0] = cvtpk(f0.x, f0.y); bf.u[1] = cvtpk(f0.z, f0.w);
    bf.u[2] = cvtpk(f1.x, f1.y); bf.u[3] = cvtpk(f1.z, f1.w);
    float w2v = f0.x * f0.x;
    w2v = fmaf(f0.y, f0.y, w2v); w2v = fmaf(f0.z, f0.z, w2v);
    w2v = fmaf(f0.w, f0.w, w2v); w2v = fmaf(f1.x, f1.x, w2v);
    w2v = fmaf(f1.y, f1.y, w2v); w2v = fmaf(f1.z, f1.z, w2v);
    w2v = fmaf(f1.w, f1.w, w2v);
    w2v += __shfl_xor(w2v, 16);
    w2v += __shfl_xor(w2v, 32);

    __syncthreads();

    // ---- Phase A: 16 independent {b128 A-frag -> MFMA -> d2 regs}
    float dA[64];
    #pragma unroll
    for (int i = 0; i < 16; ++i) {
        const int tt = (wv << 4) + i;               // t-tile 0..127
        int b0 = (tt << 4) + r + (q << 3);          // window start
        b0 = b0 > 2040 ? 2040 : b0;                 // clamp (masked rows only)
        FragU af;
        af.q = *(const uint4*)&xs8[((b0 & 7) * 257 + (b0 >> 3)) << 2];
        f32x4 z = {0.0f, 0.0f, 0.0f, 0.0f};
        const f32x4 acc = __builtin_amdgcn_mfma_f32_16x16x32_bf16(af.v, bf.v, z, 0, 0, 0);
        // C: col = lane&15 (=n), row = 4q + j -> t = 16tt + 4q + j
        const f32x4 sv = *(const f32x4*)&ssl[(tt << 4) + (q << 2)];
        dA[4 * i + 0] = fmaf(-2.0f, acc[0], sv[0] + w2v);
        dA[4 * i + 1] = fmaf(-2.0f, acc[1], sv[1] + w2v);
        dA[4 * i + 2] = fmaf(-2.0f, acc[2], sv[2] + w2v);
        dA[4 * i + 3] = fmaf(-2.0f, acc[3], sv[3] + w2v);
    }

    // ---- Phase B: block-global min per n
    float m0 = dA[0];
    #pragma unroll
    for (int k = 1; k < 64; ++k) m0 = fminf(m0, dA[k]);
    m0 = fminf(m0, __shfl_xor(m0, 16));
    m0 = fminf(m0, __shfl_xor(m0, 32));
    if (lane < 16) red[wv][r] = m0;
    __syncthreads();
    if (tid < 16) {
        float g = red[0][tid];
        #pragma unroll
        for (int wq = 1; wq < 8; ++wq) g = fminf(g, red[wq][tid]);
        gml[tid] = g;
    }
    __syncthreads();

    // ---- Phase C: 64 independent exps vs global min, 4-way accumulators
    const float g0 = gml[r];
    float sa0 = 0.0f, sa1 = 0.0f, sa2 = 0.0f, sa3 = 0.0f;
    #pragma unroll
    for (int k = 0; k < 64; k += 4) {
        sa0 += fexp2(K10 * (g0 - dA[k + 0]));
        sa1 += fexp2(K10 * (g0 - dA[k + 1]));
        sa2 += fexp2(K10 * (g0 - dA[k + 2]));
        sa3 += fexp2(K10 * (g0 - dA[k + 3]));
    }
    float S = (sa0 + sa1) + (sa2 + sa3);
    S += __shfl_xor(S, 16);
    S += __shfl_xor(S, 32);
    if (lane < 16) red[wv][r] = S;
    __syncthreads();

    // ---- final: sum 8 wave partials, write pred + dmin
    if (tid < 16) {
        float Ssum = red[0][tid];
        #pragma unroll
        for (int wq = 1; wq < 8; ++wq) Ssum += red[wq][tid];
        const float g = gml[tid];
        const int o = (b << 8) + (((ntile << 4) + tid) << 3) + m;
        out[o]        = expf(-g + 0.1f * logf(Ssum));
        out[2048 + o] = sqrtf(fmaxf(g, 0.0f));
    }
}

extern "C" void kernel_launch(void* const* d_in, const int* in_sizes, int n_in,
                              void* d_out, int out_size, void* d_ws, size_t ws_size,
                              hipStream_t stream) {
    const float* x = (const float*)d_in[0];   // (8,8,2048)
    const float* w = (const float*)d_in[1];   // (32,8,32)
    float* out = (float*)d_out;               // 4096 floats
    hipLaunchKernelGGL(shapelet_mfma, dim3(128), dim3(512), 0, stream, x, w, out);
}